// Round 14
// baseline (345.473 us; speedup 1.0000x reference)
//
#include <hip/hip_runtime.h>
#include <hip/hip_fp16.h>

#define NN 32      // nodes
#define FF 64      // GAT out features
#define HH 128     // LSTM hidden
#define G4 512     // 4*H
#define BB 32      // batch
#define TT 512     // time steps
#define ET 128     // 96 edges + 32 self loops
#define NPOS (BB*TT)
#define POSB 32    // positions per gatxw block

__device__ __forceinline__ float frcp(float x) { return __builtin_amdgcn_rcpf(x); }

// ---------------- prep: fold GAT linear + MFMA B-fragment weight transpose (R25-verified) ----
// Wt16[tid*128 + (g*4+q)*8 + e] = f16(W_hh[(q*32 + (l>>4)*8 + e)][g*128 + w*16 + (l&15)])
__global__ __launch_bounds__(512) void prep_kernel(const float* __restrict__ w_gat,
                                                   const float* __restrict__ b_gat,
                                                   const float* __restrict__ W_ih,
                                                   const float* __restrict__ W_hh,
                                                   float* __restrict__ W_eff,
                                                   float* __restrict__ biasp,
                                                   float* __restrict__ Wt) {
  int j = threadIdx.x;
  int n = blockIdx.x;
  float accw = 0.f, accb = 0.f;
#pragma unroll 8
  for (int f = 0; f < FF; ++f) {
    float wv = W_ih[(n * FF + f) * G4 + j];
    accw = fmaf(w_gat[f], wv, accw);
    accb = fmaf(b_gat[f], wv, accb);
  }
  W_eff[n * G4 + j] = accw;
  biasp[n * G4 + j] = accb;
  __half* Wt16 = (__half*)Wt;
  int g0 = (n * G4 + j) * 4;
#pragma unroll
  for (int qq = 0; qq < 4; ++qq) {
    int E = g0 + qq;
    int tl = E >> 7;             // lstm thread 0..511
    int idx = E & 127;
    int frag = idx >> 3;         // 0..15
    int e = idx & 7;
    int g = frag >> 2, q = frag & 3;
    int w = tl >> 6, l = tl & 63;
    int k = q * 32 + ((l >> 4) * 8) + e;
    int col = g * 128 + w * 16 + (l & 15);
    Wt16[E] = __float2half(W_hh[k * G4 + col]);
  }
}

// ---------------- gatxw (R26): softmax only -> sl16 (the GEMV moved into the scan MFMA) ----
__global__ __launch_bounds__(256) void gatxw_kernel(const float* __restrict__ x_seq,
                                                    const int* __restrict__ ei,
                                                    const float* __restrict__ w_gat,
                                                    const float* __restrict__ att_src,
                                                    const float* __restrict__ att_dst,
                                                    __half* __restrict__ sl16) {
  __shared__ int srt[ET];
  __shared__ int offs[NN + 1];
  __shared__ int cnt[NN];
  __shared__ float xs[POSB * NN];   // 1024
  __shared__ float scal_sh[2];
  int tid = threadIdx.x;
  int posbase = blockIdx.x * POSB;
  if (tid < NN) cnt[tid] = 0;
  __syncthreads();
  int es = 0, ed = 0, tk = 0;
  if (tid < ET) {
    if (tid < 96) { es = ei[tid]; ed = ei[96 + tid]; }
    else { es = tid - 96; ed = tid - 96; }
    tk = atomicAdd(&cnt[ed], 1);
  }
  __syncthreads();
  if (tid == 0) {
    offs[0] = 0;
    for (int n = 0; n < NN; ++n) offs[n + 1] = offs[n] + cnt[n];
  }
  if (tid == 1) {
    float cs = 0.f, cd = 0.f;
    for (int f = 0; f < FF; ++f) {
      cs = fmaf(w_gat[f], att_src[f], cs);
      cd = fmaf(w_gat[f], att_dst[f], cd);
    }
    scal_sh[0] = cs;
    scal_sh[1] = cd;
  }
  __syncthreads();
  if (tid < ET) srt[offs[ed] + tk] = es;
#pragma unroll
  for (int c = 0; c < POSB * NN / 256; ++c)
    xs[c * 256 + tid] = x_seq[posbase * NN + c * 256 + tid];  // coalesced
  __syncthreads();
  float cs = scal_sh[0], cd = scal_sh[1];
  int n = tid & 31;
  int e0 = offs[n], e1 = offs[n + 1];
#pragma unroll
  for (int pb = 0; pb < POSB / 8; ++pb) {
    int p = pb * 8 + (tid >> 5);
    int base = p * 32;
    float xn = xs[base + n];
    float cdxn = cd * xn;
    float m = -3.0e38f;
    for (int e = e0; e < e1; ++e) {
      float ev = fmaf(cs, xs[base + srt[e]], cdxn);
      ev = ev > 0.f ? ev : 0.2f * ev;  // LeakyReLU(0.2)
      m = fmaxf(m, ev);
    }
    float z = 0.f, sa = 0.f;
    for (int e = e0; e < e1; ++e) {
      float xsv = xs[base + srt[e]];
      float ev = fmaf(cs, xsv, cdxn);
      ev = ev > 0.f ? ev : 0.2f * ev;
      float ex = __expf(ev - m);
      z += ex;
      sa = fmaf(ex, xsv, sa);
    }
    sl16[(size_t)(posbase + p) * 32 + n] = __float2half(sa * frcp(z));
  }
}

// ---------------- LSTM scan: R26 — R25 MFMA core + sl->x via one extra MFMA_Q ----------------
// x_t = W_eff^T sl_t + bias as a K=32 MFMA: A = sl_t broadcast (16B/lane/step, dwordx4 ring),
// B = W_eff f16 frags (v128-143, gathered in prologue via LDS), bias -> acc reg0 init
// (v232-235). The sl-MFMA issues BEFORE the h ds_reads complete -> hides under LDS latency.
// Prologue: per thread, gather 32 W_eff f16 + 4 bias f32 from prep outputs (L2) -> LDS tmp
// -> 5 ds_read_b128 into fixed regs.
//
// Regs: v32-47 A h-frags | v64-127 h-weights | v128-143 We frags | v194 sl addr |
// v195/196 rdA/B | v197/198 wrA/B | v199 c | v200/201 consts | v203 tmp addr |
// v204-211 act temps | v216-231 acc | v232-235 bias | v240-247 sl ring

#define MFMA_Q(AQ, BI, BF, BG, BO) \
  "v_mfma_f32_16x16x32_f16 v[216:219], v[" AQ "], v[" BI "], v[216:219]\n\t" \
  "v_mfma_f32_16x16x32_f16 v[220:223], v[" AQ "], v[" BF "], v[220:223]\n\t" \
  "v_mfma_f32_16x16x32_f16 v[224:227], v[" AQ "], v[" BG "], v[224:227]\n\t" \
  "v_mfma_f32_16x16x32_f16 v[228:231], v[" AQ "], v[" BO "], v[228:231]\n\t"

#define PHASE(SLQ, RD, WR) \
  "s_waitcnt vmcnt(1)\n\t" \
  "v_mov_b32 v216, v232\n\t" \
  "v_mov_b32 v220, v233\n\t" \
  "v_mov_b32 v224, v234\n\t" \
  "v_mov_b32 v228, v235\n\t" \
  "ds_read_b128 v[32:35], " RD "\n\t" \
  "ds_read_b128 v[36:39], " RD " offset:64\n\t" \
  "ds_read_b128 v[40:43], " RD " offset:128\n\t" \
  "ds_read_b128 v[44:47], " RD " offset:192\n\t" \
  MFMA_Q(SLQ, "128:131", "132:135", "136:139", "140:143") \
  "s_waitcnt lgkmcnt(3)\n\t" \
  MFMA_Q("32:35", "64:67",   "80:83",   "96:99",   "112:115") \
  "s_waitcnt lgkmcnt(2)\n\t" \
  MFMA_Q("36:39", "68:71",   "84:87",   "100:103", "116:119") \
  "s_waitcnt lgkmcnt(1)\n\t" \
  MFMA_Q("40:43", "72:75",   "88:91",   "104:107", "120:123") \
  "s_waitcnt lgkmcnt(0)\n\t" \
  MFMA_Q("44:47", "76:79",   "92:95",   "108:111", "124:127") \
  "global_load_dwordx4 v[" SLQ "], v194, %[slb]\n\t" \
  "v_add_u32 v194, 64, v194\n\t" \
  "s_nop 7\n\t" \
  "s_nop 7\n\t" \
  "v_mul_f32 v204, v200, v216\n\t" \
  "v_mul_f32 v205, v200, v220\n\t" \
  "v_mul_f32 v206, v201, v224\n\t" \
  "v_mul_f32 v207, v200, v228\n\t" \
  "v_exp_f32 v204, v204\n\t" \
  "v_exp_f32 v205, v205\n\t" \
  "v_exp_f32 v206, v206\n\t" \
  "v_exp_f32 v207, v207\n\t" \
  "v_add_f32 v204, 1.0, v204\n\t" \
  "v_add_f32 v205, 1.0, v205\n\t" \
  "v_add_f32 v206, 1.0, v206\n\t" \
  "v_add_f32 v207, 1.0, v207\n\t" \
  "v_rcp_f32 v204, v204\n\t" \
  "v_rcp_f32 v205, v205\n\t" \
  "v_rcp_f32 v206, v206\n\t" \
  "v_rcp_f32 v207, v207\n\t" \
  "v_fma_f32 v206, -2.0, v206, 1.0\n\t" \
  "v_mul_f32 v210, v204, v206\n\t" \
  "v_fma_f32 v199, v205, v199, v210\n\t" \
  "v_mul_f32 v211, v201, v199\n\t" \
  "v_exp_f32 v211, v211\n\t" \
  "s_nop 0\n\t" \
  "v_add_f32 v211, 1.0, v211\n\t" \
  "v_rcp_f32 v211, v211\n\t" \
  "s_nop 0\n\t" \
  "v_fma_f32 v211, -2.0, v211, 1.0\n\t" \
  "v_mul_f32 v211, v207, v211\n\t" \
  "v_cvt_f16_f32 v211, v211\n\t" \
  "ds_write_b16 " WR ", v211\n\t" \
  "s_waitcnt lgkmcnt(0)\n\t" \
  "s_barrier\n\t"

__global__ __launch_bounds__(512, 2) void lstm_kernel(const __half* __restrict__ sl16,
                                                      const float* __restrict__ Wt,
                                                      const float* __restrict__ W_eff,
                                                      const float* __restrict__ biasp,
                                                      const float* __restrict__ b_ih,
                                                      const float* __restrict__ b_hh,
                                                      const float* __restrict__ W_fc,
                                                      const float* __restrict__ b_fc,
                                                      float* __restrict__ out) {
  __shared__ __align__(16) float shm[128 + 10240];  // hlds 512B + tmp 40KB
  float* hlds = shm;
  int b = blockIdx.x, tid = threadIdx.x;
  int w = tid >> 6, l = tid & 63;
  int u = w * 16 + (l & 15);                 // hidden unit (4-way redundant over l>>4)
  int kc = (l >> 4) * 8;                     // k-chunk base
  // prologue: gather We f16 frags + bias into LDS tmp (prep outputs are L2-resident)
  {
    unsigned* tp = (unsigned*)&shm[128];
    int base = tid * 20;
#pragma unroll
    for (int g = 0; g < 4; ++g) {
      int col = g * 128 + u;
      float bb = b_ih[col] + b_hh[col];
#pragma unroll 8
      for (int n = 0; n < NN; ++n) bb += biasp[n * G4 + col];
#pragma unroll
      for (int j = 0; j < 4; ++j) {
        unsigned lo = (unsigned)__half_as_ushort(__float2half(W_eff[(kc + 2 * j) * G4 + col]));
        unsigned hi = (unsigned)__half_as_ushort(__float2half(W_eff[(kc + 2 * j + 1) * G4 + col]));
        tp[base + g * 4 + j] = lo | (hi << 16);
      }
      tp[base + 16 + g] = __float_as_uint(bb);
    }
  }
  if (tid < 128) hlds[tid] = 0.f;
  const __half* slb = sl16 + (size_t)b * TT * 32;
  unsigned xoff0 = (unsigned)(kc * 2);       // 16B chunk within 64B sl row
  unsigned wtoff = (unsigned)(tid * 256);    // 128 f16 = 256 B per thread (h weights)
  unsigned lbase = (unsigned)(uintptr_t)&shm[0];   // LDS aperture is 4GB-aligned
  unsigned tmpoff = lbase + 512u + (unsigned)(tid * 80);
  unsigned rda = lbase + (unsigned)(kc * 2); // A-frag k-chunk base in h16 bufA
  unsigned rdb = rda + 256;
  unsigned wra = lbase + (unsigned)(u * 2);  // f16 element; 4-way same-addr write
  unsigned wrb = wra + 256;
  __syncthreads();
  asm volatile(
    "v_mov_b32 v194, %[xo]\n\t"
    "v_mov_b32 v195, %[rda]\n\t"
    "v_mov_b32 v196, %[rdb]\n\t"
    "v_mov_b32 v197, %[wra]\n\t"
    "v_mov_b32 v198, %[wrb]\n\t"
    "v_mov_b32 v199, 0\n\t"                   // c
    "v_mov_b32 v200, 0xbfb8aa3b\n\t"          // -log2e
    "v_mov_b32 v201, 0x4038aa3b\n\t"          // 2*log2e
    "v_mov_b32 v203, %[tmp]\n\t"
    // zero acc regs 1-3 rows (never read; bounded growth)
    "v_mov_b32 v217, 0\n\t" "v_mov_b32 v218, 0\n\t" "v_mov_b32 v219, 0\n\t"
    "v_mov_b32 v221, 0\n\t" "v_mov_b32 v222, 0\n\t" "v_mov_b32 v223, 0\n\t"
    "v_mov_b32 v225, 0\n\t" "v_mov_b32 v226, 0\n\t" "v_mov_b32 v227, 0\n\t"
    "v_mov_b32 v229, 0\n\t" "v_mov_b32 v230, 0\n\t" "v_mov_b32 v231, 0\n\t"
    // We frags + bias from LDS tmp
    "ds_read_b128 v[128:131], v203\n\t"
    "ds_read_b128 v[132:135], v203 offset:16\n\t"
    "ds_read_b128 v[136:139], v203 offset:32\n\t"
    "ds_read_b128 v[140:143], v203 offset:48\n\t"
    "ds_read_b128 v[232:235], v203 offset:64\n\t"
    // sl ring: t=0 -> v240-243, t=1 -> v244-247
    "global_load_dwordx4 v[240:243], v194, %[slb]\n\t"
    "v_add_u32 v194, 64, v194\n\t"
    "global_load_dwordx4 v[244:247], v194, %[slb]\n\t"
    "v_add_u32 v194, 64, v194\n\t"
    // 128 f16 h-weight B-frags -> v64..v127 (16 x dwordx4)
    "global_load_dwordx4 v[64:67], %[wto], %[wtb] offset:0\n\t"
    "global_load_dwordx4 v[68:71], %[wto], %[wtb] offset:16\n\t"
    "global_load_dwordx4 v[72:75], %[wto], %[wtb] offset:32\n\t"
    "global_load_dwordx4 v[76:79], %[wto], %[wtb] offset:48\n\t"
    "global_load_dwordx4 v[80:83], %[wto], %[wtb] offset:64\n\t"
    "global_load_dwordx4 v[84:87], %[wto], %[wtb] offset:80\n\t"
    "global_load_dwordx4 v[88:91], %[wto], %[wtb] offset:96\n\t"
    "global_load_dwordx4 v[92:95], %[wto], %[wtb] offset:112\n\t"
    "global_load_dwordx4 v[96:99], %[wto], %[wtb] offset:128\n\t"
    "global_load_dwordx4 v[100:103], %[wto], %[wtb] offset:144\n\t"
    "global_load_dwordx4 v[104:107], %[wto], %[wtb] offset:160\n\t"
    "global_load_dwordx4 v[108:111], %[wto], %[wtb] offset:176\n\t"
    "global_load_dwordx4 v[112:115], %[wto], %[wtb] offset:192\n\t"
    "global_load_dwordx4 v[116:119], %[wto], %[wtb] offset:208\n\t"
    "global_load_dwordx4 v[120:123], %[wto], %[wtb] offset:224\n\t"
    "global_load_dwordx4 v[124:127], %[wto], %[wtb] offset:240\n\t"
    "s_waitcnt vmcnt(0) lgkmcnt(0)\n\t"
    "s_movk_i32 s20, 0x100\n\t"    // 256 iterations x 2 phases = 512 steps
    "L_lstm_%=:\n\t"
    PHASE("240:243", "v195", "v198")   // t even: read h bufA, write bufB
    PHASE("244:247", "v196", "v197")   // t odd:  read bufB, write bufA
    "s_sub_u32 s20, s20, 1\n\t"
    "s_cmp_lg_u32 s20, 0\n\t"
    "s_cbranch_scc1 L_lstm_%=\n\t"
    "s_waitcnt vmcnt(0) lgkmcnt(0)\n\t"
    :
    : [slb]"s"(slb), [wtb]"s"(Wt), [wto]"v"(wtoff), [xo]"v"(xoff0),
      [rda]"v"(rda), [rdb]"v"(rdb), [wra]"v"(wra), [wrb]"v"(wrb), [tmp]"v"(tmpoff)
    : "memory", "scc", "s20",
      "v32","v33","v34","v35","v36","v37","v38","v39",
      "v40","v41","v42","v43","v44","v45","v46","v47",
      "v64","v65","v66","v67","v68","v69","v70","v71",
      "v72","v73","v74","v75","v76","v77","v78","v79",
      "v80","v81","v82","v83","v84","v85","v86","v87",
      "v88","v89","v90","v91","v92","v93","v94","v95",
      "v96","v97","v98","v99","v100","v101","v102","v103",
      "v104","v105","v106","v107","v108","v109","v110","v111",
      "v112","v113","v114","v115","v116","v117","v118","v119",
      "v120","v121","v122","v123","v124","v125","v126","v127",
      "v128","v129","v130","v131","v132","v133","v134","v135",
      "v136","v137","v138","v139","v140","v141","v142","v143",
      "v194","v195","v196","v197","v198","v199","v200","v201",
      "v202","v203","v204","v205","v206","v207","v208","v209",
      "v210","v211","v216","v217","v218","v219","v220","v221",
      "v222","v223","v224","v225","v226","v227","v228","v229",
      "v230","v231","v232","v233","v234","v235",
      "v240","v241","v242","v243","v244","v245","v246","v247");
  __syncthreads();
  // final h (after t=511, odd -> buffer A): f16 linear hlds bytes [0,256)
  if (tid < 4) {
    const __half* hf = (const __half*)hlds;
    float acc = b_fc[tid];
#pragma unroll 8
    for (int k = 0; k < HH; ++k)
      acc = fmaf(__half2float(hf[k]), W_fc[k * 4 + tid], acc);
    out[b * 4 + tid] = acc;
  }
}

extern "C" void kernel_launch(void* const* d_in, const int* in_sizes, int n_in,
                              void* d_out, int out_size, void* d_ws, size_t ws_size,
                              hipStream_t stream) {
  const float* x_seq   = (const float*)d_in[0];
  const int*   ei      = (const int*)d_in[1];
  const float* w_gat   = (const float*)d_in[2];
  const float* att_src = (const float*)d_in[3];
  const float* att_dst = (const float*)d_in[4];
  const float* b_gat   = (const float*)d_in[5];
  const float* W_ih    = (const float*)d_in[6];
  const float* W_hh    = (const float*)d_in[7];
  const float* b_ih    = (const float*)d_in[8];
  const float* b_hh    = (const float*)d_in[9];
  const float* W_fc    = (const float*)d_in[10];
  const float* b_fc    = (const float*)d_in[11];

  float* ws = (float*)d_ws;
  float* Wt    = ws;                            // 65536 f16 used (reserved 65536 f32)
  __half* sl16 = (__half*)(ws + 65536);         // (NPOS+16)*32 halves = 262400 f32 slots
  float* W_eff = ws + 65536 + 262400;           // 32*512
  float* biasp = W_eff + NN * G4;               // 32*512

  prep_kernel<<<NN, G4, 0, stream>>>(w_gat, b_gat, W_ih, W_hh, W_eff, biasp, Wt);
  gatxw_kernel<<<NPOS / POSB, 256, 0, stream>>>(x_seq, ei, w_gat, att_src, att_dst, sl16);
  lstm_kernel<<<BB, G4, 0, stream>>>(sl16, Wt, W_eff, biasp, b_ih, b_hh, W_fc, b_fc,
                                     (float*)d_out);
}